// Round 1
// 59472.699 us; speedup vs baseline: 2.5418x; 2.5418x over previous
//
#include <hip/hip_runtime.h>
#include <hip/hip_cooperative_groups.h>
#include <cmath>

namespace cg = cooperative_groups;

// Problem dims (from reference setup_inputs)
#define T_STEPS 2048
#define BATCH   32
#define NN      2048
#define BN      (BATCH * NN)

// Launch shape: 512 blocks x 256 threads, cooperative (2 blocks/CU on 256 CUs)
#define NBLK     512
#define NTHREADS 256
#define NJ       4              // output columns per block (NBLK*NJ == NN)
#define KSEC     4              // K-split sections per block
#define KLEN     (NN / KSEC)    // 512
#define WPAD     8              // +8 floats/row: js=2 row lands 16 banks away -> conflict-free b128

// ---- fast grid barrier state ----
// Zero-initialized at module load. Counters are MONOTONE (never reset); each
// launch reads a base value at a quiescent point (before the one CG sync) and
// spins on base-relative targets, so repeated launches are safe.
__device__ unsigned g_bar_sub[8 * 16];   // 8 sub-counters, 64 B apart
__device__ unsigned g_bar_root[16];      // root counter (+8 per barrier epoch)

__global__ __launch_bounds__(NTHREADS)
void lif_persistent(const float* __restrict__ x_in,
                    const float* __restrict__ v0,
                    const float* __restrict__ s0,
                    const float* __restrict__ w,
                    const float* __restrict__ E_L,
                    const float* __restrict__ tau_m,
                    const float* __restrict__ tau_s,
                    const int*   __restrict__ ntypes,
                    float*       __restrict__ out,
                    float*       __restrict__ ws)
{
    cg::grid_group grid = cg::this_grid();

    // W_eff^T slice for this block's 4 columns: wT[jl][i], rows padded +8 floats
    // so the two j-halves read by one wave instruction hit disjoint bank groups.
    __shared__ float wT[NJ][NN + WPAD];
    __shared__ float red[KSEC][BATCH][NJ];

    float* sbuf0 = ws;            // s state, ping   (layout: sT[n][b], [N][B])
    float* sbuf1 = ws + BN;       // s state, pong

    const int blk = blockIdx.x;
    const int tid = threadIdx.x;
    const int j0  = blk * NJ;

    // ---- one-time: preload W_eff^T slice into LDS (W never touched again) ----
    for (int i = tid; i < NN; i += NTHREADS) {
        const float4 wv = *reinterpret_cast<const float4*>(w + (size_t)i * NN + j0);
        const float nt = (float)ntypes[i];
        float w0 = wv.x * nt, w1 = wv.y * nt, w2 = wv.z * nt, w3 = wv.w * nt;
        if (i == j0    ) w0 = 0.0f;   // self-recurrence mask (diag = 0)
        if (i == j0 + 1) w1 = 0.0f;
        if (i == j0 + 2) w2 = 0.0f;
        if (i == j0 + 3) w3 = 0.0f;
        wT[0][i] = w0; wT[1][i] = w1; wT[2][i] = w2; wT[3][i] = w3;
    }

    // ---- one-time: init s state, TRANSPOSED to sT[n][b] so phase-1 wave reads
    // are 32 contiguous dwords (2 cache lines/instr) instead of 32 lines. ----
    for (int idx = blk * NTHREADS + tid; idx < BN; idx += NBLK * NTHREADS) {
        const int bb = idx >> 11;          // idx / NN
        const int nn = idx & (NN - 1);     // idx % NN
        sbuf0[nn * BATCH + bb] = s0[idx];  // coalesced read, one-time scatter
    }

    // GEMM mapping: 4 waves = 4 K-sections; within a wave, lane -> (b, j-half)
    const int ksec = tid >> 6;          // 0..3
    const int lane = tid & 63;
    const int b    = lane >> 1;         // 0..31
    const int js   = (lane & 1) * 2;    // 0 or 2 (two adjacent j's per thread)

    // Phase-2 mapping: threads 0..127 each own one (batch, neuron) state cell
    const bool p2 = (tid < BATCH * NJ);
    const int  b2 = tid >> 2;
    const int  jl = tid & 3;
    const int  jg = j0 + jl;
    float el = 0.f, tm = 1.f, ts = 1.f, nR = 0.f, dvmax = 1.f;
    float vreg = 0.f, sreg = 0.f;
    size_t idxBN = 0;                   // [B][N] index for x_in / out
    int    idxT  = 0;                   // [N][B] index for s buffers
    if (p2) {
        el    = E_L[jg];
        tm    = tau_m[jg];
        ts    = tau_s[jg];
        nR    = (30.0f - el) * 1.1f;   // (THRESH - E_L) * R_CONST
        dvmax = 30.0f - el;            // THRESH - E_L
        idxBN = (size_t)b2 * NN + jg;
        idxT  = jg * BATCH + b2;
        vreg  = v0[idxBN];             // v state: register-resident whole run
        sreg  = s0[idxBN];             // own copy of s state
    }

    // Read barrier base while counters are guaranteed quiescent (no block can
    // reach a fast barrier until after grid.sync below).
    unsigned bar_base = 0;
    if (tid == 0)
        bar_base = __hip_atomic_load(&g_bar_root[0], __ATOMIC_RELAXED,
                                     __HIP_MEMORY_SCOPE_AGENT);

    grid.sync();   // one-time CG sync: publishes LDS-independent init (s0 scatter)

    for (int t = 0; t < T_STEPS; ++t) {
        const float* __restrict__ sread  = (t & 1) ? sbuf1 : sbuf0;
        float*       __restrict__ swrite = (t & 1) ? sbuf0 : sbuf1;

        // Prefetch this step's x early; consumed after the GEMM (latency hidden)
        float xv = 0.0f;
        if (p2) xv = __builtin_nontemporal_load(x_in + (size_t)t * BN + idxBN);

        // ---- phase 1: partial dot products, K-section ksec ----
        // s is [N][B]: wave's 32 b-lanes read 128 contiguous bytes per k.
        float acc0 = 0.0f, acc1 = 0.0f;
        {
            const float* __restrict__ scol = sread + b;   // lane's batch column
            const int i0 = ksec * KLEN;
            #pragma unroll 4
            for (int i = i0; i < i0 + KLEN; i += 4) {
                const float sv0 = scol[(i + 0) * BATCH];
                const float sv1 = scol[(i + 1) * BATCH];
                const float sv2 = scol[(i + 2) * BATCH];
                const float sv3 = scol[(i + 3) * BATCH];
                const float4 wa = *reinterpret_cast<const float4*>(&wT[js][i]);
                const float4 wb = *reinterpret_cast<const float4*>(&wT[js + 1][i]);
                acc0 = fmaf(sv0, wa.x, acc0); acc1 = fmaf(sv0, wb.x, acc1);
                acc0 = fmaf(sv1, wa.y, acc0); acc1 = fmaf(sv1, wb.y, acc1);
                acc0 = fmaf(sv2, wa.z, acc0); acc1 = fmaf(sv2, wb.z, acc1);
                acc0 = fmaf(sv3, wa.w, acc0); acc1 = fmaf(sv3, wb.w, acc1);
            }
        }
        red[ksec][b][js]     = acc0;
        red[ksec][b][js + 1] = acc1;
        __syncthreads();

        // ---- phase 2: K-reduce + LIF update + output (threads 0..127) ----
        if (p2) {
            const float dot = red[0][b2][jl] + red[1][b2][jl]
                            + red[2][b2][jl] + red[3][b2][jl];
            const float I   = dot + 1.75f * xv;          // INPUT_GAIN * x
            const float dv  = ((el - vreg) + I * nR) / tm;
            const float vn  = vreg + dv;
            float gating = vn / 30.0f;
            gating = fminf(fmaxf(gating, 0.0f), 1.0f);
            float cdv = dv / dvmax;
            cdv = fminf(fmaxf(cdv, 0.0f), 1.0f);
            const float snew = sreg + (gating * cdv - sreg) / ts;
            // Agent-scope store (sc0 sc1): lands at the LLC (coherence point),
            // never dirty in the local L2 -> no per-step L2 writeback needed.
            __hip_atomic_store(&swrite[idxT], snew, __ATOMIC_RELAXED,
                               __HIP_MEMORY_SCOPE_AGENT);
            sreg = snew;
            vreg = (vn >= 30.0f) ? el : vn;              // spike reset
            const float sig = 1.0f / (1.0f + expf(30.0f - vn));
            __builtin_nontemporal_store(sig, out + (size_t)t * BN + idxBN);
        }

        // ---- fast grid barrier (replaces cg::grid.sync: no buffer_wbl2) ----
        __syncthreads();   // all waves drain vmcnt (incl. agent s-stores) here
        if (tid == 0) {
            asm volatile("s_waitcnt vmcnt(0)" ::: "memory");  // belt & suspenders
            const unsigned old = __hip_atomic_fetch_add(
                &g_bar_sub[(blk & 7) * 16], 1u,
                __ATOMIC_RELAXED, __HIP_MEMORY_SCOPE_AGENT);
            if ((old & 63u) == 63u)     // last of this 64-block group this epoch
                __hip_atomic_fetch_add(&g_bar_root[0], 1u,
                                       __ATOMIC_RELAXED, __HIP_MEMORY_SCOPE_AGENT);
            const unsigned tgt = bar_base + 8u * (unsigned)(t + 1);
            while ((int)(__hip_atomic_load(&g_bar_root[0], __ATOMIC_RELAXED,
                                           __HIP_MEMORY_SCOPE_AGENT) - tgt) < 0)
                __builtin_amdgcn_s_sleep(8);
        }
        __syncthreads();
        // Acquire: buffer_inv (L1+L2 invalidate, no writeback) so next step's
        // normal cached s-loads refill fresh from the LLC.
        __builtin_amdgcn_fence(__ATOMIC_ACQUIRE, "agent");
    }
}

extern "C" void kernel_launch(void* const* d_in, const int* in_sizes, int n_in,
                              void* d_out, int out_size, void* d_ws, size_t ws_size,
                              hipStream_t stream) {
    (void)in_sizes; (void)n_in; (void)out_size; (void)ws_size;
    const float* x_in   = (const float*)d_in[0];
    const float* v0     = (const float*)d_in[1];
    const float* s0     = (const float*)d_in[2];
    const float* w      = (const float*)d_in[3];
    const float* E_L    = (const float*)d_in[4];
    const float* tau_m  = (const float*)d_in[5];
    const float* tau_s  = (const float*)d_in[6];
    const int*   ntypes = (const int*)d_in[7];
    float* out = (float*)d_out;
    float* ws  = (float*)d_ws;   // needs 2*BN floats = 512 KB

    void* args[] = { (void*)&x_in, (void*)&v0, (void*)&s0, (void*)&w,
                     (void*)&E_L, (void*)&tau_m, (void*)&tau_s, (void*)&ntypes,
                     (void*)&out, (void*)&ws };
    hipLaunchCooperativeKernel((const void*)lif_persistent,
                               dim3(NBLK), dim3(NTHREADS), args, 0, stream);
}